// Round 8
// baseline (610.563 us; speedup 1.0000x reference)
//
#include <hip/hip_runtime.h>
#include <hip/hip_bf16.h>

// ---------------- constants ----------------
#define NUM_USERS 50000
#define NUM_ITEMS 20000
#define NUM_NODES (NUM_USERS + NUM_ITEMS)
#define FEAT_DIM 768
#define HID 128
#define H1DIM 512
#define LN_EPS 1e-5f
#define ALPHA 0.25f
#define NBKT 137   // ceil(70000/512) coarse buckets
#define SPLIT 35000  // src-half split for L2-resident gather phases

typedef __attribute__((ext_vector_type(8))) short short8;
typedef __attribute__((ext_vector_type(4))) float floatx4;

// bf16 round-to-nearest-even
static __device__ inline unsigned short f2bf(float f) {
  unsigned int u = __float_as_uint(f);
  u += 0x7fffu + ((u >> 16) & 1u);
  return (unsigned short)(u >> 16);
}
static __device__ inline float bflo(unsigned int u) {
  return __uint_as_float(u << 16);
}
static __device__ inline float bfhi(unsigned int u) {
  return __uint_as_float(u & 0xffff0000u);
}

// -------- cast fp32 -> bf16, 8 elements/thread, exact grid -------------------
__global__ __launch_bounds__(256) void cast_bf16(
    const float* __restrict__ in, unsigned short* __restrict__ out) {
  size_t i = (size_t)blockIdx.x * 256 + threadIdx.x;
  float4 u = ((const float4*)in)[i * 2];
  float4 v = ((const float4*)in)[i * 2 + 1];
  union { unsigned short s[8]; uint4 q; } p;
  p.s[0] = f2bf(u.x); p.s[1] = f2bf(u.y); p.s[2] = f2bf(u.z); p.s[3] = f2bf(u.w);
  p.s[4] = f2bf(v.x); p.s[5] = f2bf(v.y); p.s[6] = f2bf(v.z); p.s[7] = f2bf(v.w);
  ((uint4*)out)[i] = p.q;
}

// -------- transpose+cast: W[K x N] fp32 -> Wt[N x K] bf16 --------------------
__global__ __launch_bounds__(256) void transpose_cast(
    const float* __restrict__ W, unsigned short* __restrict__ Wt,
    int K, int N) {
  __shared__ float tile[32][33];
  int tx = threadIdx.x, ty = threadIdx.y;
  int bx = blockIdx.x, by = blockIdx.y;
#pragma unroll
  for (int kk = 0; kk < 4; kk++)
    tile[ty + kk * 8][tx] = W[(size_t)(by * 32 + ty + kk * 8) * N + bx * 32 + tx];
  __syncthreads();
#pragma unroll
  for (int kk = 0; kk < 4; kk++)
    Wt[(size_t)(bx * 32 + ty + kk * 8) * K + by * 32 + tx] =
        f2bf(tile[tx][ty + kk * 8]);
}

// -------- bf16 MFMA GEMM: C(MxN) fp32 = A(MxK) . Bt(NxK)^T + bias ------------
__global__ __launch_bounds__(256) void gemm_mfma_bias(
    const unsigned short* __restrict__ A, const unsigned short* __restrict__ Bt,
    const float* __restrict__ bias, float* __restrict__ C,
    int M, int N, int K) {
  __shared__ __align__(16) unsigned short As[128 * 32];
  __shared__ __align__(16) unsigned short Bs[128 * 32];
  const int tid = threadIdx.x;
  const int wave = tid >> 6, lane = tid & 63;
  const int quad = lane >> 4, l16 = lane & 15;
  const int wm = wave >> 1, wn = wave & 1;
  const int bm = blockIdx.y * 128, bn = blockIdx.x * 128;

  floatx4 acc[4][4];
#pragma unroll
  for (int i = 0; i < 4; i++)
#pragma unroll
    for (int j = 0; j < 4; j++) acc[i][j] = (floatx4){0.f, 0.f, 0.f, 0.f};

  const int srow = lane >> 2;
  const int scol = (lane & 3) * 8;

  for (int k0 = 0; k0 < K; k0 += 32) {
#pragma unroll
    for (int i = 0; i < 2; i++) {
      int c = wave * 2 + i;
      int arow = bm + c * 16 + srow;
      if (arow >= M) arow = M - 1;
      const unsigned short* ga = A + (size_t)arow * K + k0 + scol;
      __builtin_amdgcn_global_load_lds(
          (const __attribute__((address_space(1))) unsigned int*)(uintptr_t)ga,
          (__attribute__((address_space(3))) unsigned int*)(uintptr_t)(As + c * 512),
          16, 0, 0);
      int brow = bn + c * 16 + srow;
      const unsigned short* gb = Bt + (size_t)brow * K + k0 + scol;
      __builtin_amdgcn_global_load_lds(
          (const __attribute__((address_space(1))) unsigned int*)(uintptr_t)gb,
          (__attribute__((address_space(3))) unsigned int*)(uintptr_t)(Bs + c * 512),
          16, 0, 0);
    }
    __syncthreads();

    short8 af[4], bf[4];
#pragma unroll
    for (int i = 0; i < 4; i++) {
      af[i] = *(const short8*)&As[(wm * 64 + i * 16 + l16) * 32 + quad * 8];
      bf[i] = *(const short8*)&Bs[(wn * 64 + i * 16 + l16) * 32 + quad * 8];
    }
#pragma unroll
    for (int i = 0; i < 4; i++)
#pragma unroll
      for (int j = 0; j < 4; j++)
        acc[i][j] = __builtin_amdgcn_mfma_f32_16x16x32_bf16(af[i], bf[j],
                                                            acc[i][j], 0, 0, 0);
    __syncthreads();
  }

#pragma unroll
  for (int i = 0; i < 4; i++) {
    int row0 = bm + wm * 64 + i * 16 + quad * 4;
#pragma unroll
    for (int j = 0; j < 4; j++) {
      int col = bn + wn * 64 + j * 16 + l16;
      float bv = bias[col];
#pragma unroll
      for (int r = 0; r < 4; r++) {
        int row = row0 + r;
        if (row < M) C[(size_t)row * N + col] = acc[i][j][r] + bv;
      }
    }
  }
}

// ---- LayerNorm+ReLU width 512, fp32 in -> bf16 out --------------------------
__global__ __launch_bounds__(256) void ln_relu_w512_bf16(
    const float* __restrict__ X, const float* __restrict__ g,
    const float* __restrict__ be, unsigned short* __restrict__ O) {
  int row = blockIdx.x, t = threadIdx.x;
  const float* x = X + (size_t)row * H1DIM;
  float v0 = x[t], v1 = x[t + 256];
  float s = v0 + v1, q = v0 * v0 + v1 * v1;
#pragma unroll
  for (int off = 32; off > 0; off >>= 1) {
    s += __shfl_down(s, off);
    q += __shfl_down(q, off);
  }
  __shared__ float ss[4], qq[4];
  int lane = t & 63, wid = t >> 6;
  if (lane == 0) { ss[wid] = s; qq[wid] = q; }
  __syncthreads();
  float S = ss[0] + ss[1] + ss[2] + ss[3];
  float Q = qq[0] + qq[1] + qq[2] + qq[3];
  float mu = S * (1.f / 512.f);
  float var = Q * (1.f / 512.f) - mu * mu;
  float rs = rsqrtf(var + LN_EPS);
  float y0 = (v0 - mu) * rs * g[t] + be[t];
  float y1 = (v1 - mu) * rs * g[t + 256] + be[t + 256];
  unsigned short* o = O + (size_t)row * H1DIM;
  o[t] = f2bf(fmaxf(y0, 0.f));
  o[t + 256] = f2bf(fmaxf(y1, 0.f));
}

// ---------------- LayerNorm+ReLU, width 128, one wave per row ----------------
__global__ __launch_bounds__(256) void ln_relu_w128(
    float* __restrict__ X, const float* __restrict__ g,
    const float* __restrict__ be, int rows) {
  int gwid = (blockIdx.x * blockDim.x + threadIdx.x) >> 6;
  if (gwid >= rows) return;
  int lane = threadIdx.x & 63;
  float* x = X + (size_t)gwid * HID;
  float v0 = x[lane], v1 = x[lane + 64];
  float s = v0 + v1, q = v0 * v0 + v1 * v1;
#pragma unroll
  for (int off = 32; off > 0; off >>= 1) {
    s += __shfl_down(s, off);
    q += __shfl_down(q, off);
  }
  s = __shfl(s, 0);
  q = __shfl(q, 0);
  float mu = s * (1.f / 128.f);
  float var = q * (1.f / 128.f) - mu * mu;
  float rs = rsqrtf(var + LN_EPS);
  float y0 = (v0 - mu) * rs * g[lane] + be[lane];
  float y1 = (v1 - mu) * rs * g[lane + 64] + be[lane + 64];
  x[lane] = fmaxf(y0, 0.f);
  x[lane + 64] = fmaxf(y1, 0.f);
}

// ---- GEMM3 (128x128) + L2-normalize, 4 rows/block ---------------------------
__global__ __launch_bounds__(128) void gemm3_norm4(
    const float* __restrict__ H, const float* __restrict__ W3,
    const float* __restrict__ b3, float* __restrict__ meta) {
  int r0 = blockIdx.x * 4, t = threadIdx.x;
  __shared__ float hrow[4][HID];
#pragma unroll
  for (int r = 0; r < 4; r++) hrow[r][t] = H[(size_t)(r0 + r) * HID + t];
  __syncthreads();
  float s0 = 0.f, s1 = 0.f, s2 = 0.f, s3 = 0.f;
#pragma unroll 4
  for (int k = 0; k < HID; k++) {
    float w = W3[k * HID + t];
    s0 = fmaf(hrow[0][k], w, s0);
    s1 = fmaf(hrow[1][k], w, s1);
    s2 = fmaf(hrow[2][k], w, s2);
    s3 = fmaf(hrow[3][k], w, s3);
  }
  float b = b3[t];
  s0 += b; s1 += b; s2 += b; s3 += b;
  float q0 = s0 * s0, q1 = s1 * s1, q2 = s2 * s2, q3 = s3 * s3;
#pragma unroll
  for (int off = 32; off > 0; off >>= 1) {
    q0 += __shfl_down(q0, off);
    q1 += __shfl_down(q1, off);
    q2 += __shfl_down(q2, off);
    q3 += __shfl_down(q3, off);
  }
  __shared__ float qs[4][2];
  if ((t & 63) == 0) {
    int w = t >> 6;
    qs[0][w] = q0; qs[1][w] = q1; qs[2][w] = q2; qs[3][w] = q3;
  }
  __syncthreads();
  float n0 = fmaxf(sqrtf(qs[0][0] + qs[0][1]), 1e-12f);
  float n1 = fmaxf(sqrtf(qs[1][0] + qs[1][1]), 1e-12f);
  float n2 = fmaxf(sqrtf(qs[2][0] + qs[2][1]), 1e-12f);
  float n3 = fmaxf(sqrtf(qs[3][0] + qs[3][1]), 1e-12f);
  meta[(size_t)(r0 + 0) * HID + t] = s0 / n0;
  meta[(size_t)(r0 + 1) * HID + t] = s1 / n1;
  meta[(size_t)(r0 + 2) * HID + t] = s2 / n2;
  meta[(size_t)(r0 + 3) * HID + t] = s3 / n3;
}

// --------- build e0: out = alpha*e0 (fp32), xs0 = bf16(dinv*e0) chunk-major --
// xs layout: xs[chunk][node][32 feats] -> 16 uints per (chunk,node), 64 B.
// dinv[src] pre-folded: y[r] = dinv[r] * sum_e xs[s].
__global__ __launch_bounds__(256) void build_e0_cm4(
    const float* __restrict__ emb, const float* __restrict__ meta,
    const float* __restrict__ mw_p, const float* __restrict__ dinv,
    unsigned int* __restrict__ x0c, float* __restrict__ out) {
  size_t i = (size_t)blockIdx.x * 256 + threadIdx.x;  // 70000*64 uints, exact
  int node = (int)(i >> 6);
  int u6 = (int)(i & 63);
  int chunk = u6 >> 4, fl = u6 & 15;
  int f0 = chunk * 32 + fl * 2;
  float2 e = *(const float2*)&emb[(size_t)node * HID + f0];
  if (node >= NUM_USERS) {
    float2 m = *(const float2*)&meta[(size_t)(node - NUM_USERS) * HID + f0];
    float w = mw_p[0];
    e.x += w * m.x;
    e.y += w * m.y;
  }
  *(float2*)&out[(size_t)node * HID + f0] = make_float2(ALPHA * e.x, ALPHA * e.y);
  float d = dinv[node];
  unsigned pk = (unsigned)f2bf(d * e.x) | ((unsigned)f2bf(d * e.y) << 16);
  x0c[((size_t)chunk * NUM_NODES + node) * 16 + fl] = pk;
}

// ======== atomic-free CSR build: two-level bucket sort =======================
__global__ __launch_bounds__(256) void p1_hist(const int* __restrict__ dst,
                                               int* __restrict__ ghist,
                                               int E, int NBL) {
  __shared__ int h[NBKT];
  int t = threadIdx.x;
  if (t < NBKT) h[t] = 0;
  __syncthreads();
  int base = blockIdx.x * 8192;
  for (int i = t; i < 8192; i += 256) {
    int e = base + i;
    if (e < E) atomicAdd(&h[dst[e] >> 9], 1);
  }
  __syncthreads();
  if (t < NBKT) ghist[t * NBL + blockIdx.x] = h[t];
}

__global__ __launch_bounds__(256) void scan_a(const int* __restrict__ in,
                                              int* __restrict__ outp,
                                              int* __restrict__ bsum, int n) {
  int i = blockIdx.x * 256 + threadIdx.x;
  int v = (i < n) ? in[i] : 0;
  int lane = threadIdx.x & 63, wid = threadIdx.x >> 6;
  int s = v;
#pragma unroll
  for (int off = 1; off < 64; off <<= 1) {
    int u = __shfl_up(s, off);
    if (lane >= off) s += u;
  }
  __shared__ int wsum[4];
  if (lane == 63) wsum[wid] = s;
  __syncthreads();
  int add = 0;
  for (int w = 0; w < wid; w++) add += wsum[w];
  int incl = s + add;
  if (i < n) outp[i] = incl - v;
  if (threadIdx.x == 255) bsum[blockIdx.x] = incl;
}

__global__ __launch_bounds__(512) void scan_b(int* __restrict__ bsum, int nb) {
  int t = threadIdx.x;
  int v = (t < nb) ? bsum[t] : 0;
  int lane = t & 63, wid = t >> 6;
  int s = v;
#pragma unroll
  for (int off = 1; off < 64; off <<= 1) {
    int u = __shfl_up(s, off);
    if (lane >= off) s += u;
  }
  __shared__ int ws[8];
  if (lane == 63) ws[wid] = s;
  __syncthreads();
  int add = 0;
  for (int w = 0; w < wid; w++) add += ws[w];
  if (t < nb) bsum[t] = s + add - v;
}

__global__ __launch_bounds__(256) void scan_c(int* __restrict__ outp,
                                              const int* __restrict__ bsum,
                                              int n) {
  int i = blockIdx.x * 256 + threadIdx.x;
  if (i < n) outp[i] += bsum[blockIdx.x];
}

__global__ __launch_bounds__(256) void p1_scatter(
    const int* __restrict__ src, const int* __restrict__ dst,
    const int* __restrict__ gscan, unsigned long long* __restrict__ pairs,
    int E, int NBL) {
  __shared__ int cur[NBKT];
  int t = threadIdx.x;
  if (t < NBKT) cur[t] = gscan[t * NBL + blockIdx.x];
  __syncthreads();
  int base = blockIdx.x * 8192;
  for (int i = t; i < 8192; i += 256) {
    int e = base + i;
    if (e < E) {
      int d = dst[e];
      int pos = atomicAdd(&cur[d >> 9], 1);
      pairs[pos] = ((unsigned long long)(unsigned)d << 32) | (unsigned)src[e];
    }
  }
}

// p2_build2: within each 512-node bucket, bin by (node, src-half) -> rowptr2
// rowptr2[2i] = row i begin, rowptr2[2i+1] = row i src-half split, contiguous.
__global__ __launch_bounds__(512) void p2_build2(
    const unsigned long long* __restrict__ pairs,
    const int* __restrict__ gscan, int* __restrict__ rowptr2,
    int* __restrict__ csr_src, int E, int NBL) {
  __shared__ int hist[1024];
  __shared__ int ws8[8];
  int b = blockIdx.x, t = threadIdx.x;
  int base = gscan[b * NBL];
  int end = (b == NBKT - 1) ? E : gscan[(b + 1) * NBL];
  hist[t] = 0;
  hist[t + 512] = 0;
  __syncthreads();
  for (int i = base + t; i < end; i += 512) {
    unsigned long long p = pairs[i];
    unsigned d = (unsigned)(p >> 32);
    unsigned s = (unsigned)p;
    atomicAdd(&hist[((d & 511) << 1) | (s >= SPLIT)], 1);
  }
  __syncthreads();
  int v0 = hist[2 * t], v1 = hist[2 * t + 1];
  int pv = v0 + v1;
  int lane = t & 63, wid = t >> 6;
  int s = pv;
#pragma unroll
  for (int off = 1; off < 64; off <<= 1) {
    int u = __shfl_up(s, off);
    if (lane >= off) s += u;
  }
  if (lane == 63) ws8[wid] = s;
  __syncthreads();
  int add = 0;
  for (int w = 0; w < wid; w++) add += ws8[w];
  int excl = s + add - pv;
  int p0 = base + excl;
  int p1 = p0 + v0;
  int node = (b << 9) + t;
  if (node < NUM_NODES) {
    rowptr2[2 * node] = p0;
    rowptr2[2 * node + 1] = p1;
  }
  if (b == NBKT - 1 && t == 0) rowptr2[2 * NUM_NODES] = E;
  __syncthreads();
  hist[2 * t] = p0;
  hist[2 * t + 1] = p1;
  __syncthreads();
  for (int i = base + t; i < end; i += 512) {
    unsigned long long p = pairs[i];
    unsigned d = (unsigned)(p >> 32);
    unsigned sv = (unsigned)p;
    int pos = atomicAdd(&hist[((d & 511) << 1) | (sv >= SPLIT)], 1);
    csr_src[pos] = (int)sv;
  }
}

__global__ __launch_bounds__(256) void calc_dinv2s(
    const int* __restrict__ rowptr2, float* __restrict__ dinv, int n) {
  int i = blockIdx.x * 256 + threadIdx.x;
  if (i < n) {
    int d = rowptr2[2 * i + 2] - rowptr2[2 * i];
    dinv[i] = d > 0 ? rsqrtf((float)d) : 0.f;
  }
}

// ------- chunked SpMM v7: 4 chunks x 32 feats, src-half phased gathers -------
// chunk = blockIdx & 3. Wave = 8 row-slots x 8 lanes; lane owns uint2 (4 feats).
// Phase h gathers only sources in half h -> live gather set 2.24 MB/XCD
// (L2-resident), same 64B requests, same accumulator across phases.
#define ACC1(v)                 \
  {                             \
    a0 += bflo((v).x);          \
    a1 += bfhi((v).x);          \
    a2 += bflo((v).y);          \
    a3 += bfhi((v).y);          \
  }

__global__ __launch_bounds__(256) void spmm_chunk4h(
    const int* __restrict__ rowptr2, const int* __restrict__ csrc,
    const float* __restrict__ dinv, const uint2* __restrict__ xc,
    uint2* __restrict__ yc, float* __restrict__ out, int write_y) {
  int chunk = blockIdx.x & 3;
  int rowblk = blockIdx.x >> 2;
  int tid = threadIdx.x;
  int wave = tid >> 6, lane = tid & 63;
  int slot = lane >> 3, fl = lane & 7;
  int row = rowblk * 32 + wave * 8 + slot;
  bool act = row < NUM_NODES;
  int rr = act ? row : NUM_NODES - 1;
  int beg = rowptr2[2 * rr], mid = rowptr2[2 * rr + 1], e2 = rowptr2[2 * rr + 2];
  float wd = dinv[rr];
  const uint2* xq = xc + (size_t)chunk * NUM_NODES * 8 + fl;  // 8 uint2/node
  float a0 = 0.f, a1 = 0.f, a2 = 0.f, a3 = 0.f;
#pragma unroll 1
  for (int h = 0; h < 2; h++) {
    int p = h ? mid : beg;
    int e = h ? e2 : mid;
    // align p to a multiple of 4 so uint4 loads of the src stream are aligned
    int na = (p + 3) & ~3;
    if (na > e) na = e;
    for (; p < na; p++) {
      int s = csrc[p];
      uint2 v = xq[(size_t)(unsigned)s * 8];
      ACC1(v)
    }
    for (; p + 8 <= e; p += 8) {
      uint4 sA = *(const uint4*)(csrc + p);
      uint4 sB = *(const uint4*)(csrc + p + 4);
      uint2 v0 = xq[(size_t)sA.x * 8];
      uint2 v1 = xq[(size_t)sA.y * 8];
      uint2 v2 = xq[(size_t)sA.z * 8];
      uint2 v3 = xq[(size_t)sA.w * 8];
      uint2 v4 = xq[(size_t)sB.x * 8];
      uint2 v5 = xq[(size_t)sB.y * 8];
      uint2 v6 = xq[(size_t)sB.z * 8];
      uint2 v7 = xq[(size_t)sB.w * 8];
      ACC1(v0) ACC1(v1) ACC1(v2) ACC1(v3)
      ACC1(v4) ACC1(v5) ACC1(v6) ACC1(v7)
    }
    if (p + 4 <= e) {
      uint4 sA = *(const uint4*)(csrc + p);
      uint2 v0 = xq[(size_t)sA.x * 8];
      uint2 v1 = xq[(size_t)sA.y * 8];
      uint2 v2 = xq[(size_t)sA.z * 8];
      uint2 v3 = xq[(size_t)sA.w * 8];
      ACC1(v0) ACC1(v1) ACC1(v2) ACC1(v3)
      p += 4;
    }
    for (; p < e; p++) {
      int s = csrc[p];
      uint2 v = xq[(size_t)(unsigned)s * 8];
      ACC1(v)
    }
  }
  // y = dinv[row] * s
  float y0 = wd * a0, y1 = wd * a1, y2 = wd * a2, y3 = wd * a3;
  if (act) {
    if (write_y) {
      unsigned p0 = (unsigned)f2bf(wd * y0) | ((unsigned)f2bf(wd * y1) << 16);
      unsigned p1 = (unsigned)f2bf(wd * y2) | ((unsigned)f2bf(wd * y3) << 16);
      yc[((size_t)chunk * NUM_NODES + row) * 8 + fl] = make_uint2(p0, p1);
    }
    float4* op = (float4*)&out[(size_t)row * HID + chunk * 32 + fl * 4];
    float4 po = *op;
    po.x += ALPHA * y0;
    po.y += ALPHA * y1;
    po.z += ALPHA * y2;
    po.w += ALPHA * y3;
    *op = po;
  }
}

// ---------------- launcher ---------------------------------------------------
extern "C" void kernel_launch(void* const* d_in, const int* in_sizes, int n_in,
                              void* d_out, int out_size, void* d_ws,
                              size_t ws_size, hipStream_t stream) {
  const int* edge = (const int*)d_in[0];
  const float* item_feat = (const float*)d_in[1];
  const float* emb = (const float*)d_in[2];
  const float* W1 = (const float*)d_in[3];
  const float* b1 = (const float*)d_in[4];
  const float* g1 = (const float*)d_in[5];
  const float* be1 = (const float*)d_in[6];
  const float* W2 = (const float*)d_in[7];
  const float* b2 = (const float*)d_in[8];
  const float* g2 = (const float*)d_in[9];
  const float* be2 = (const float*)d_in[10];
  const float* W3 = (const float*)d_in[11];
  const float* b3 = (const float*)d_in[12];
  const float* mw = (const float*)d_in[13];
  float* out = (float*)d_out;

  const int E = in_sizes[0] / 2;
  const int* src = edge;
  const int* dst = edge + E;
  const int NBL = (E + 8191) / 8192;        // 245 P1 blocks
  const int nScan = NBKT * NBL;             // 33565
  const int NBs = (nScan + 255) / 256;      // 132

  // workspace layout (lifetimes disjoint on the single stream):
  //  [0, 40.96M)        h1 fp32 (dead after ln_relu_w512); then:
  //                       pairs@0 (16M, dead after p2_build2),
  //                       rowptr2@16M (560KB), dinv@16.6M, ghist@16.9M,
  //                       gscan@17.1M, bsum@17.3M, csr_src@17.5M (8M),
  //                       meta@26M (10.24M, written by gemm3 before CSR build)
  //  [40.96M, 51.2M)    h2 fp32
  //  [51.2M, 71.68M)    h1b bf16; then xA_cm bf16 chunk-major (17.92M)
  //  [87.04M, 117.76M)  Af bf16; then xB_cm (17.92M)
  //  [104.96M, 122.88M) xC_cm (17.92M, Af dead by then)
  //  [122.88M, ...)     W1t, W2t bf16
  char* ws = (char*)d_ws;
  float* h1 = (float*)(ws + 0);
  float* h2 = (float*)(ws + 40960000);
  unsigned short* h1b = (unsigned short*)(ws + 51200000);
  uint2* xA = (uint2*)(ws + 51200000);
  unsigned short* Af = (unsigned short*)(ws + 87040000);
  uint2* xB = (uint2*)(ws + 87040000);
  uint2* xC = (uint2*)(ws + 104960000);
  unsigned short* W1t = (unsigned short*)(ws + 122880000);
  unsigned short* W2t = (unsigned short*)(ws + 123666432);
  float* meta = (float*)(ws + 26000000);  // clear of CSR scratch [16M,25.5M)

  unsigned long long* pairs = (unsigned long long*)(ws + 0);
  int* rowptr2 = (int*)(ws + 16000000);   // (2*NUM_NODES+1) ints = 560 KB
  float* dinv = (float*)(ws + 16600000);
  int* ghist = (int*)(ws + 16900000);
  int* gscan = (int*)(ws + 17100000);
  int* bsum = (int*)(ws + 17300000);
  int* csr_src = (int*)(ws + 17500000);

  // ---- casts ----
  cast_bf16<<<(NUM_ITEMS * FEAT_DIM / 8) / 256, 256, 0, stream>>>(item_feat, Af);
  transpose_cast<<<dim3(H1DIM / 32, FEAT_DIM / 32), dim3(32, 8), 0, stream>>>(
      W1, W1t, FEAT_DIM, H1DIM);
  transpose_cast<<<dim3(HID / 32, H1DIM / 32), dim3(32, 8), 0, stream>>>(
      W2, W2t, H1DIM, HID);

  // ---- item metadata MLP (bf16 MFMA GEMMs) ----
  gemm_mfma_bias<<<dim3(H1DIM / 128, (NUM_ITEMS + 127) / 128), 256, 0, stream>>>(
      Af, W1t, b1, h1, NUM_ITEMS, H1DIM, FEAT_DIM);
  ln_relu_w512_bf16<<<NUM_ITEMS, 256, 0, stream>>>(h1, g1, be1, h1b);
  gemm_mfma_bias<<<dim3(HID / 128, (NUM_ITEMS + 127) / 128), 256, 0, stream>>>(
      h1b, W2t, b2, h2, NUM_ITEMS, HID, H1DIM);
  ln_relu_w128<<<(NUM_ITEMS * 64) / 256, 256, 0, stream>>>(h2, g2, be2,
                                                           NUM_ITEMS);
  gemm3_norm4<<<NUM_ITEMS / 4, 128, 0, stream>>>(h2, W3, b3, meta);

  // ---- atomic-free CSR build with per-row src-half split ----
  p1_hist<<<NBL, 256, 0, stream>>>(dst, ghist, E, NBL);
  scan_a<<<NBs, 256, 0, stream>>>(ghist, gscan, bsum, nScan);
  scan_b<<<1, 512, 0, stream>>>(bsum, NBs);
  scan_c<<<NBs, 256, 0, stream>>>(gscan, bsum, nScan);
  p1_scatter<<<NBL, 256, 0, stream>>>(src, dst, gscan, pairs, E, NBL);
  p2_build2<<<NBKT, 512, 0, stream>>>(pairs, gscan, rowptr2, csr_src, E, NBL);
  calc_dinv2s<<<(NUM_NODES + 255) / 256, 256, 0, stream>>>(rowptr2, dinv,
                                                           NUM_NODES);

  // ---- e0 -> out (fp32) + xs0 = bf16(dinv*e0), 4 chunks x 32 feats ----
  build_e0_cm4<<<(NUM_NODES * 64) / 256, 256, 0, stream>>>(
      emb, meta, mw, dinv, (unsigned int*)xA, out);

  // ---- 3 propagation layers (4-chunked, src-half phased) ----
  const int RG = ((NUM_NODES + 31) / 32) * 4;  // 2188*4 = 8752 blocks
  spmm_chunk4h<<<RG, 256, 0, stream>>>(rowptr2, csr_src, dinv, xA, xB, out, 1);
  spmm_chunk4h<<<RG, 256, 0, stream>>>(rowptr2, csr_src, dinv, xB, xC, out, 1);
  spmm_chunk4h<<<RG, 256, 0, stream>>>(rowptr2, csr_src, dinv, xC, nullptr, out, 0);
}

// Round 9
// 551.966 us; speedup vs baseline: 1.1062x; 1.1062x over previous
//
#include <hip/hip_runtime.h>
#include <hip/hip_bf16.h>

// ---------------- constants ----------------
#define NUM_USERS 50000
#define NUM_ITEMS 20000
#define NUM_NODES (NUM_USERS + NUM_ITEMS)
#define FEAT_DIM 768
#define HID 128
#define H1DIM 512
#define LN_EPS 1e-5f
#define ALPHA 0.25f
#define NBKT 137  // ceil(70000/512) coarse buckets

typedef __attribute__((ext_vector_type(8))) short short8;
typedef __attribute__((ext_vector_type(4))) float floatx4;

// bf16 round-to-nearest-even
static __device__ inline unsigned short f2bf(float f) {
  unsigned int u = __float_as_uint(f);
  u += 0x7fffu + ((u >> 16) & 1u);
  return (unsigned short)(u >> 16);
}
static __device__ inline float bflo(unsigned int u) {
  return __uint_as_float(u << 16);
}
static __device__ inline float bfhi(unsigned int u) {
  return __uint_as_float(u & 0xffff0000u);
}

// -------- cast fp32 -> bf16, 8 elements/thread, exact grid -------------------
__global__ __launch_bounds__(256) void cast_bf16(
    const float* __restrict__ in, unsigned short* __restrict__ out) {
  size_t i = (size_t)blockIdx.x * 256 + threadIdx.x;
  float4 u = ((const float4*)in)[i * 2];
  float4 v = ((const float4*)in)[i * 2 + 1];
  union { unsigned short s[8]; uint4 q; } p;
  p.s[0] = f2bf(u.x); p.s[1] = f2bf(u.y); p.s[2] = f2bf(u.z); p.s[3] = f2bf(u.w);
  p.s[4] = f2bf(v.x); p.s[5] = f2bf(v.y); p.s[6] = f2bf(v.z); p.s[7] = f2bf(v.w);
  ((uint4*)out)[i] = p.q;
}

// -------- transpose+cast: W[K x N] fp32 -> Wt[N x K] bf16 --------------------
__global__ __launch_bounds__(256) void transpose_cast(
    const float* __restrict__ W, unsigned short* __restrict__ Wt,
    int K, int N) {
  __shared__ float tile[32][33];
  int tx = threadIdx.x, ty = threadIdx.y;
  int bx = blockIdx.x, by = blockIdx.y;
#pragma unroll
  for (int kk = 0; kk < 4; kk++)
    tile[ty + kk * 8][tx] = W[(size_t)(by * 32 + ty + kk * 8) * N + bx * 32 + tx];
  __syncthreads();
#pragma unroll
  for (int kk = 0; kk < 4; kk++)
    Wt[(size_t)(bx * 32 + ty + kk * 8) * K + by * 32 + tx] =
        f2bf(tile[tx][ty + kk * 8]);
}

// -------- bf16 MFMA GEMM: C(MxN) fp32 = A(MxK) . Bt(NxK)^T + bias ------------
__global__ __launch_bounds__(256) void gemm_mfma_bias(
    const unsigned short* __restrict__ A, const unsigned short* __restrict__ Bt,
    const float* __restrict__ bias, float* __restrict__ C,
    int M, int N, int K) {
  __shared__ __align__(16) unsigned short As[128 * 32];
  __shared__ __align__(16) unsigned short Bs[128 * 32];
  const int tid = threadIdx.x;
  const int wave = tid >> 6, lane = tid & 63;
  const int quad = lane >> 4, l16 = lane & 15;
  const int wm = wave >> 1, wn = wave & 1;
  const int bm = blockIdx.y * 128, bn = blockIdx.x * 128;

  floatx4 acc[4][4];
#pragma unroll
  for (int i = 0; i < 4; i++)
#pragma unroll
    for (int j = 0; j < 4; j++) acc[i][j] = (floatx4){0.f, 0.f, 0.f, 0.f};

  const int srow = lane >> 2;
  const int scol = (lane & 3) * 8;

  for (int k0 = 0; k0 < K; k0 += 32) {
#pragma unroll
    for (int i = 0; i < 2; i++) {
      int c = wave * 2 + i;
      int arow = bm + c * 16 + srow;
      if (arow >= M) arow = M - 1;
      const unsigned short* ga = A + (size_t)arow * K + k0 + scol;
      __builtin_amdgcn_global_load_lds(
          (const __attribute__((address_space(1))) unsigned int*)(uintptr_t)ga,
          (__attribute__((address_space(3))) unsigned int*)(uintptr_t)(As + c * 512),
          16, 0, 0);
      int brow = bn + c * 16 + srow;
      const unsigned short* gb = Bt + (size_t)brow * K + k0 + scol;
      __builtin_amdgcn_global_load_lds(
          (const __attribute__((address_space(1))) unsigned int*)(uintptr_t)gb,
          (__attribute__((address_space(3))) unsigned int*)(uintptr_t)(Bs + c * 512),
          16, 0, 0);
    }
    __syncthreads();

    short8 af[4], bf[4];
#pragma unroll
    for (int i = 0; i < 4; i++) {
      af[i] = *(const short8*)&As[(wm * 64 + i * 16 + l16) * 32 + quad * 8];
      bf[i] = *(const short8*)&Bs[(wn * 64 + i * 16 + l16) * 32 + quad * 8];
    }
#pragma unroll
    for (int i = 0; i < 4; i++)
#pragma unroll
      for (int j = 0; j < 4; j++)
        acc[i][j] = __builtin_amdgcn_mfma_f32_16x16x32_bf16(af[i], bf[j],
                                                            acc[i][j], 0, 0, 0);
    __syncthreads();
  }

#pragma unroll
  for (int i = 0; i < 4; i++) {
    int row0 = bm + wm * 64 + i * 16 + quad * 4;
#pragma unroll
    for (int j = 0; j < 4; j++) {
      int col = bn + wn * 64 + j * 16 + l16;
      float bv = bias[col];
#pragma unroll
      for (int r = 0; r < 4; r++) {
        int row = row0 + r;
        if (row < M) C[(size_t)row * N + col] = acc[i][j][r] + bv;
      }
    }
  }
}

// ---- LayerNorm+ReLU width 512, fp32 in -> bf16 out --------------------------
__global__ __launch_bounds__(256) void ln_relu_w512_bf16(
    const float* __restrict__ X, const float* __restrict__ g,
    const float* __restrict__ be, unsigned short* __restrict__ O) {
  int row = blockIdx.x, t = threadIdx.x;
  const float* x = X + (size_t)row * H1DIM;
  float v0 = x[t], v1 = x[t + 256];
  float s = v0 + v1, q = v0 * v0 + v1 * v1;
#pragma unroll
  for (int off = 32; off > 0; off >>= 1) {
    s += __shfl_down(s, off);
    q += __shfl_down(q, off);
  }
  __shared__ float ss[4], qq[4];
  int lane = t & 63, wid = t >> 6;
  if (lane == 0) { ss[wid] = s; qq[wid] = q; }
  __syncthreads();
  float S = ss[0] + ss[1] + ss[2] + ss[3];
  float Q = qq[0] + qq[1] + qq[2] + qq[3];
  float mu = S * (1.f / 512.f);
  float var = Q * (1.f / 512.f) - mu * mu;
  float rs = rsqrtf(var + LN_EPS);
  float y0 = (v0 - mu) * rs * g[t] + be[t];
  float y1 = (v1 - mu) * rs * g[t + 256] + be[t + 256];
  unsigned short* o = O + (size_t)row * H1DIM;
  o[t] = f2bf(fmaxf(y0, 0.f));
  o[t + 256] = f2bf(fmaxf(y1, 0.f));
}

// ---------------- LayerNorm+ReLU, width 128, one wave per row ----------------
__global__ __launch_bounds__(256) void ln_relu_w128(
    float* __restrict__ X, const float* __restrict__ g,
    const float* __restrict__ be, int rows) {
  int gwid = (blockIdx.x * blockDim.x + threadIdx.x) >> 6;
  if (gwid >= rows) return;
  int lane = threadIdx.x & 63;
  float* x = X + (size_t)gwid * HID;
  float v0 = x[lane], v1 = x[lane + 64];
  float s = v0 + v1, q = v0 * v0 + v1 * v1;
#pragma unroll
  for (int off = 32; off > 0; off >>= 1) {
    s += __shfl_down(s, off);
    q += __shfl_down(q, off);
  }
  s = __shfl(s, 0);
  q = __shfl(q, 0);
  float mu = s * (1.f / 128.f);
  float var = q * (1.f / 128.f) - mu * mu;
  float rs = rsqrtf(var + LN_EPS);
  float y0 = (v0 - mu) * rs * g[lane] + be[lane];
  float y1 = (v1 - mu) * rs * g[lane + 64] + be[lane + 64];
  x[lane] = fmaxf(y0, 0.f);
  x[lane + 64] = fmaxf(y1, 0.f);
}

// ---- GEMM3 (128x128) + L2-normalize, 4 rows/block ---------------------------
__global__ __launch_bounds__(128) void gemm3_norm4(
    const float* __restrict__ H, const float* __restrict__ W3,
    const float* __restrict__ b3, float* __restrict__ meta) {
  int r0 = blockIdx.x * 4, t = threadIdx.x;
  __shared__ float hrow[4][HID];
#pragma unroll
  for (int r = 0; r < 4; r++) hrow[r][t] = H[(size_t)(r0 + r) * HID + t];
  __syncthreads();
  float s0 = 0.f, s1 = 0.f, s2 = 0.f, s3 = 0.f;
#pragma unroll 4
  for (int k = 0; k < HID; k++) {
    float w = W3[k * HID + t];
    s0 = fmaf(hrow[0][k], w, s0);
    s1 = fmaf(hrow[1][k], w, s1);
    s2 = fmaf(hrow[2][k], w, s2);
    s3 = fmaf(hrow[3][k], w, s3);
  }
  float b = b3[t];
  s0 += b; s1 += b; s2 += b; s3 += b;
  float q0 = s0 * s0, q1 = s1 * s1, q2 = s2 * s2, q3 = s3 * s3;
#pragma unroll
  for (int off = 32; off > 0; off >>= 1) {
    q0 += __shfl_down(q0, off);
    q1 += __shfl_down(q1, off);
    q2 += __shfl_down(q2, off);
    q3 += __shfl_down(q3, off);
  }
  __shared__ float qs[4][2];
  if ((t & 63) == 0) {
    int w = t >> 6;
    qs[0][w] = q0; qs[1][w] = q1; qs[2][w] = q2; qs[3][w] = q3;
  }
  __syncthreads();
  float n0 = fmaxf(sqrtf(qs[0][0] + qs[0][1]), 1e-12f);
  float n1 = fmaxf(sqrtf(qs[1][0] + qs[1][1]), 1e-12f);
  float n2 = fmaxf(sqrtf(qs[2][0] + qs[2][1]), 1e-12f);
  float n3 = fmaxf(sqrtf(qs[3][0] + qs[3][1]), 1e-12f);
  meta[(size_t)(r0 + 0) * HID + t] = s0 / n0;
  meta[(size_t)(r0 + 1) * HID + t] = s1 / n1;
  meta[(size_t)(r0 + 2) * HID + t] = s2 / n2;
  meta[(size_t)(r0 + 3) * HID + t] = s3 / n3;
}

// --------- build e0: out = alpha*e0 (fp32), xs0 = bf16(dinv*e0), 2 chunks ----
// xs layout: xs[chunk][node][64 feats] -> 32 uints per (chunk,node), 128 B.
// dinv[src] pre-folded: y[r] = dinv[r] * sum_e xs[s].
__global__ __launch_bounds__(256) void build_e0_cm2(
    const float* __restrict__ emb, const float* __restrict__ meta,
    const float* __restrict__ mw_p, const float* __restrict__ dinv,
    unsigned int* __restrict__ x0c, float* __restrict__ out) {
  size_t i = (size_t)blockIdx.x * 256 + threadIdx.x;  // 70000*64 uints, exact
  int node = (int)(i >> 6);
  int u6 = (int)(i & 63);
  int chunk = u6 >> 5, fl32 = u6 & 31;
  int f0 = chunk * 64 + fl32 * 2;
  float2 e = *(const float2*)&emb[(size_t)node * HID + f0];
  if (node >= NUM_USERS) {
    float2 m = *(const float2*)&meta[(size_t)(node - NUM_USERS) * HID + f0];
    float w = mw_p[0];
    e.x += w * m.x;
    e.y += w * m.y;
  }
  *(float2*)&out[(size_t)node * HID + f0] = make_float2(ALPHA * e.x, ALPHA * e.y);
  float d = dinv[node];
  unsigned pk = (unsigned)f2bf(d * e.x) | ((unsigned)f2bf(d * e.y) << 16);
  x0c[((size_t)chunk * NUM_NODES + node) * 32 + fl32] = pk;
}

// ======== atomic-free CSR build: two-level bucket sort =======================
__global__ __launch_bounds__(256) void p1_hist(const int* __restrict__ dst,
                                               int* __restrict__ ghist,
                                               int E, int NBL) {
  __shared__ int h[NBKT];
  int t = threadIdx.x;
  if (t < NBKT) h[t] = 0;
  __syncthreads();
  int base = blockIdx.x * 8192;
  for (int i = t; i < 8192; i += 256) {
    int e = base + i;
    if (e < E) atomicAdd(&h[dst[e] >> 9], 1);
  }
  __syncthreads();
  if (t < NBKT) ghist[t * NBL + blockIdx.x] = h[t];
}

__global__ __launch_bounds__(256) void scan_a(const int* __restrict__ in,
                                              int* __restrict__ outp,
                                              int* __restrict__ bsum, int n) {
  int i = blockIdx.x * 256 + threadIdx.x;
  int v = (i < n) ? in[i] : 0;
  int lane = threadIdx.x & 63, wid = threadIdx.x >> 6;
  int s = v;
#pragma unroll
  for (int off = 1; off < 64; off <<= 1) {
    int u = __shfl_up(s, off);
    if (lane >= off) s += u;
  }
  __shared__ int wsum[4];
  if (lane == 63) wsum[wid] = s;
  __syncthreads();
  int add = 0;
  for (int w = 0; w < wid; w++) add += wsum[w];
  int incl = s + add;
  if (i < n) outp[i] = incl - v;
  if (threadIdx.x == 255) bsum[blockIdx.x] = incl;
}

__global__ __launch_bounds__(512) void scan_b(int* __restrict__ bsum, int nb) {
  int t = threadIdx.x;
  int v = (t < nb) ? bsum[t] : 0;
  int lane = t & 63, wid = t >> 6;
  int s = v;
#pragma unroll
  for (int off = 1; off < 64; off <<= 1) {
    int u = __shfl_up(s, off);
    if (lane >= off) s += u;
  }
  __shared__ int ws[8];
  if (lane == 63) ws[wid] = s;
  __syncthreads();
  int add = 0;
  for (int w = 0; w < wid; w++) add += ws[w];
  if (t < nb) bsum[t] = s + add - v;
}

__global__ __launch_bounds__(256) void scan_c(int* __restrict__ outp,
                                              const int* __restrict__ bsum,
                                              int n) {
  int i = blockIdx.x * 256 + threadIdx.x;
  if (i < n) outp[i] += bsum[blockIdx.x];
}

__global__ __launch_bounds__(256) void p1_scatter(
    const int* __restrict__ src, const int* __restrict__ dst,
    const int* __restrict__ gscan, unsigned long long* __restrict__ pairs,
    int E, int NBL) {
  __shared__ int cur[NBKT];
  int t = threadIdx.x;
  if (t < NBKT) cur[t] = gscan[t * NBL + blockIdx.x];
  __syncthreads();
  int base = blockIdx.x * 8192;
  for (int i = t; i < 8192; i += 256) {
    int e = base + i;
    if (e < E) {
      int d = dst[e];
      int pos = atomicAdd(&cur[d >> 9], 1);
      pairs[pos] = ((unsigned long long)(unsigned)d << 32) | (unsigned)src[e];
    }
  }
}

__global__ __launch_bounds__(512) void p2_build(
    const unsigned long long* __restrict__ pairs,
    const int* __restrict__ gscan, int* __restrict__ rowptr,
    int* __restrict__ csr_src, int E, int NBL) {
  __shared__ int hist[512];
  __shared__ int ws8[8];
  int b = blockIdx.x, t = threadIdx.x;
  int base = gscan[b * NBL];
  int end = (b == NBKT - 1) ? E : gscan[(b + 1) * NBL];
  hist[t] = 0;
  __syncthreads();
  for (int i = base + t; i < end; i += 512) {
    unsigned d = (unsigned)(pairs[i] >> 32);
    atomicAdd(&hist[d & 511], 1);
  }
  __syncthreads();
  int v = hist[t];
  int lane = t & 63, wid = t >> 6;
  int s = v;
#pragma unroll
  for (int off = 1; off < 64; off <<= 1) {
    int u = __shfl_up(s, off);
    if (lane >= off) s += u;
  }
  if (lane == 63) ws8[wid] = s;
  __syncthreads();
  int add = 0;
  for (int w = 0; w < wid; w++) add += ws8[w];
  int excl = s + add - v;
  int node = (b << 9) + t;
  if (node < NUM_NODES) rowptr[node] = base + excl;
  if (b == NBKT - 1 && t == 0) rowptr[NUM_NODES] = E;
  __syncthreads();
  hist[t] = base + excl;
  __syncthreads();
  for (int i = base + t; i < end; i += 512) {
    unsigned long long p = pairs[i];
    unsigned d = (unsigned)(p >> 32);
    int pos = atomicAdd(&hist[d & 511], 1);
    csr_src[pos] = (int)(unsigned)p;
  }
}

__global__ __launch_bounds__(256) void calc_dinv2(const int* __restrict__ rowptr,
                                                  float* __restrict__ dinv,
                                                  int n) {
  int i = blockIdx.x * 256 + threadIdx.x;
  if (i < n) {
    int d = rowptr[i + 1] - rowptr[i];
    dinv[i] = d > 0 ? rsqrtf((float)d) : 0.f;
  }
}

// ------- chunked SpMM v8: 2 chunks x 64 feats (128B gathers), 8-deep ---------
// chunk = blockIdx & 1 (chunk 0 -> even XCDs, chunk 1 -> odd XCDs).
// Wave = 4 row-slots x 16 lanes; lane owns one uint2 (4 bf16 feats).
// Halves gather-request count vs 4-chunk: time ~ requests x avg latency.
#define ACC1(v)                 \
  {                             \
    a0 += bflo((v).x);          \
    a1 += bfhi((v).x);          \
    a2 += bflo((v).y);          \
    a3 += bfhi((v).y);          \
  }

__global__ __launch_bounds__(256) void spmm_chunk2(
    const int* __restrict__ rowptr, const int* __restrict__ csrc,
    const float* __restrict__ dinv, const uint2* __restrict__ xc,
    uint2* __restrict__ yc, float* __restrict__ out, int write_y) {
  int chunk = blockIdx.x & 1;
  int rowblk = blockIdx.x >> 1;
  int tid = threadIdx.x;
  int wave = tid >> 6, lane = tid & 63;
  int slot = lane >> 4, fl = lane & 15;
  int row = rowblk * 16 + wave * 4 + slot;
  bool act = row < NUM_NODES;
  int rr = act ? row : NUM_NODES - 1;
  int beg = rowptr[rr], end = rowptr[rr + 1];
  float wd = dinv[rr];
  const uint2* xq = xc + (size_t)chunk * NUM_NODES * 16 + fl;  // 16 uint2/node
  float a0 = 0.f, a1 = 0.f, a2 = 0.f, a3 = 0.f;
  int p = beg;
  // align p to a multiple of 4 so uint4 loads of the src stream are aligned
  int na = (beg + 3) & ~3;
  if (na > end) na = end;
  for (; p < na; p++) {
    int s = csrc[p];
    uint2 v = xq[(size_t)(unsigned)s * 16];
    ACC1(v)
  }
  for (; p + 8 <= end; p += 8) {
    uint4 sA = *(const uint4*)(csrc + p);
    uint4 sB = *(const uint4*)(csrc + p + 4);
    uint2 v0 = xq[(size_t)sA.x * 16];
    uint2 v1 = xq[(size_t)sA.y * 16];
    uint2 v2 = xq[(size_t)sA.z * 16];
    uint2 v3 = xq[(size_t)sA.w * 16];
    uint2 v4 = xq[(size_t)sB.x * 16];
    uint2 v5 = xq[(size_t)sB.y * 16];
    uint2 v6 = xq[(size_t)sB.z * 16];
    uint2 v7 = xq[(size_t)sB.w * 16];
    ACC1(v0) ACC1(v1) ACC1(v2) ACC1(v3)
    ACC1(v4) ACC1(v5) ACC1(v6) ACC1(v7)
  }
  if (p + 4 <= end) {
    uint4 sA = *(const uint4*)(csrc + p);
    uint2 v0 = xq[(size_t)sA.x * 16];
    uint2 v1 = xq[(size_t)sA.y * 16];
    uint2 v2 = xq[(size_t)sA.z * 16];
    uint2 v3 = xq[(size_t)sA.w * 16];
    ACC1(v0) ACC1(v1) ACC1(v2) ACC1(v3)
    p += 4;
  }
  for (; p < end; p++) {
    int s = csrc[p];
    uint2 v = xq[(size_t)(unsigned)s * 16];
    ACC1(v)
  }
  // y = dinv[row] * s
  float y0 = wd * a0, y1 = wd * a1, y2 = wd * a2, y3 = wd * a3;
  if (act) {
    if (write_y) {
      unsigned p0 = (unsigned)f2bf(wd * y0) | ((unsigned)f2bf(wd * y1) << 16);
      unsigned p1 = (unsigned)f2bf(wd * y2) | ((unsigned)f2bf(wd * y3) << 16);
      yc[((size_t)chunk * NUM_NODES + row) * 16 + fl] = make_uint2(p0, p1);
    }
    float4* op = (float4*)&out[(size_t)row * HID + chunk * 64 + fl * 4];
    float4 po = *op;
    po.x += ALPHA * y0;
    po.y += ALPHA * y1;
    po.z += ALPHA * y2;
    po.w += ALPHA * y3;
    *op = po;
  }
}

// ---------------- launcher ---------------------------------------------------
extern "C" void kernel_launch(void* const* d_in, const int* in_sizes, int n_in,
                              void* d_out, int out_size, void* d_ws,
                              size_t ws_size, hipStream_t stream) {
  const int* edge = (const int*)d_in[0];
  const float* item_feat = (const float*)d_in[1];
  const float* emb = (const float*)d_in[2];
  const float* W1 = (const float*)d_in[3];
  const float* b1 = (const float*)d_in[4];
  const float* g1 = (const float*)d_in[5];
  const float* be1 = (const float*)d_in[6];
  const float* W2 = (const float*)d_in[7];
  const float* b2 = (const float*)d_in[8];
  const float* g2 = (const float*)d_in[9];
  const float* be2 = (const float*)d_in[10];
  const float* W3 = (const float*)d_in[11];
  const float* b3 = (const float*)d_in[12];
  const float* mw = (const float*)d_in[13];
  float* out = (float*)d_out;

  const int E = in_sizes[0] / 2;
  const int* src = edge;
  const int* dst = edge + E;
  const int NBL = (E + 8191) / 8192;        // 245 P1 blocks
  const int nScan = NBKT * NBL;             // 33565
  const int NBs = (nScan + 255) / 256;      // 132

  // workspace layout (lifetimes disjoint on the single stream):
  //  [0, 40.96M)        h1 fp32 (dead after ln_relu_w512); then:
  //                       pairs@0 (16M, dead after p2_build),
  //                       rowptr@16M, dinv@16.5M, ghist@16.8M,
  //                       gscan@17M, bsum@17.2M, csr_src@17.5M (8M),
  //                       meta@26M (10.24M, written by gemm3 before CSR build)
  //  [40.96M, 51.2M)    h2 fp32
  //  [51.2M, 71.68M)    h1b bf16; then xA_cm bf16 chunk-major (17.92M)
  //  [87.04M, 117.76M)  Af bf16; then xB_cm (17.92M)
  //  [104.96M, 122.88M) xC_cm (17.92M, Af dead by then)
  //  [122.88M, ...)     W1t, W2t bf16
  char* ws = (char*)d_ws;
  float* h1 = (float*)(ws + 0);
  float* h2 = (float*)(ws + 40960000);
  unsigned short* h1b = (unsigned short*)(ws + 51200000);
  uint2* xA = (uint2*)(ws + 51200000);
  unsigned short* Af = (unsigned short*)(ws + 87040000);
  uint2* xB = (uint2*)(ws + 87040000);
  uint2* xC = (uint2*)(ws + 104960000);
  unsigned short* W1t = (unsigned short*)(ws + 122880000);
  unsigned short* W2t = (unsigned short*)(ws + 123666432);
  float* meta = (float*)(ws + 26000000);  // clear of CSR scratch [16M,25.5M)

  unsigned long long* pairs = (unsigned long long*)(ws + 0);
  int* rowptr = (int*)(ws + 16000000);
  float* dinv = (float*)(ws + 16500000);
  int* ghist = (int*)(ws + 16800000);
  int* gscan = (int*)(ws + 17000000);
  int* bsum = (int*)(ws + 17200000);
  int* csr_src = (int*)(ws + 17500000);

  // ---- casts ----
  cast_bf16<<<(NUM_ITEMS * FEAT_DIM / 8) / 256, 256, 0, stream>>>(item_feat, Af);
  transpose_cast<<<dim3(H1DIM / 32, FEAT_DIM / 32), dim3(32, 8), 0, stream>>>(
      W1, W1t, FEAT_DIM, H1DIM);
  transpose_cast<<<dim3(HID / 32, H1DIM / 32), dim3(32, 8), 0, stream>>>(
      W2, W2t, H1DIM, HID);

  // ---- item metadata MLP (bf16 MFMA GEMMs) ----
  gemm_mfma_bias<<<dim3(H1DIM / 128, (NUM_ITEMS + 127) / 128), 256, 0, stream>>>(
      Af, W1t, b1, h1, NUM_ITEMS, H1DIM, FEAT_DIM);
  ln_relu_w512_bf16<<<NUM_ITEMS, 256, 0, stream>>>(h1, g1, be1, h1b);
  gemm_mfma_bias<<<dim3(HID / 128, (NUM_ITEMS + 127) / 128), 256, 0, stream>>>(
      h1b, W2t, b2, h2, NUM_ITEMS, HID, H1DIM);
  ln_relu_w128<<<(NUM_ITEMS * 64) / 256, 256, 0, stream>>>(h2, g2, be2,
                                                           NUM_ITEMS);
  gemm3_norm4<<<NUM_ITEMS / 4, 128, 0, stream>>>(h2, W3, b3, meta);

  // ---- atomic-free CSR build (before build_e0: it needs dinv) ----
  p1_hist<<<NBL, 256, 0, stream>>>(dst, ghist, E, NBL);
  scan_a<<<NBs, 256, 0, stream>>>(ghist, gscan, bsum, nScan);
  scan_b<<<1, 512, 0, stream>>>(bsum, NBs);
  scan_c<<<NBs, 256, 0, stream>>>(gscan, bsum, nScan);
  p1_scatter<<<NBL, 256, 0, stream>>>(src, dst, gscan, pairs, E, NBL);
  p2_build<<<NBKT, 512, 0, stream>>>(pairs, gscan, rowptr, csr_src, E, NBL);
  calc_dinv2<<<(NUM_NODES + 255) / 256, 256, 0, stream>>>(rowptr, dinv,
                                                          NUM_NODES);

  // ---- e0 -> out (fp32) + xs0 = bf16(dinv*e0), 2 chunks x 64 feats ----
  build_e0_cm2<<<(NUM_NODES * 64) / 256, 256, 0, stream>>>(
      emb, meta, mw, dinv, (unsigned int*)xA, out);

  // ---- 3 propagation layers (2-chunked, 128B gathers) ----
  const int RG = ((NUM_NODES + 15) / 16) * 2;  // 4375*2 = 8750 blocks
  spmm_chunk2<<<RG, 256, 0, stream>>>(rowptr, csr_src, dinv, xA, xB, out, 1);
  spmm_chunk2<<<RG, 256, 0, stream>>>(rowptr, csr_src, dinv, xB, xC, out, 1);
  spmm_chunk2<<<RG, 256, 0, stream>>>(rowptr, csr_src, dinv, xC, nullptr, out, 0);
}

// Round 11
// 533.814 us; speedup vs baseline: 1.1438x; 1.0340x over previous
//
#include <hip/hip_runtime.h>
#include <hip/hip_bf16.h>

// ---------------- constants ----------------
#define NUM_USERS 50000
#define NUM_ITEMS 20000
#define NUM_NODES (NUM_USERS + NUM_ITEMS)
#define FEAT_DIM 768
#define HID 128
#define H1DIM 512
#define LN_EPS 1e-5f
#define ALPHA 0.25f
#define NBKT 137  // ceil(70000/512) coarse buckets

typedef __attribute__((ext_vector_type(8))) short short8;
typedef __attribute__((ext_vector_type(4))) float floatx4;

// bf16 round-to-nearest-even
static __device__ inline unsigned short f2bf(float f) {
  unsigned int u = __float_as_uint(f);
  u += 0x7fffu + ((u >> 16) & 1u);
  return (unsigned short)(u >> 16);
}
static __device__ inline float bflo(unsigned int u) {
  return __uint_as_float(u << 16);
}
static __device__ inline float bfhi(unsigned int u) {
  return __uint_as_float(u & 0xffff0000u);
}

// ---- generic MFMA GEMM body (shared by gemm1/gemm2 call sites) --------------
static __device__ __forceinline__ void gemm_body(
    const unsigned short* __restrict__ A, const unsigned short* __restrict__ Bt,
    const float* __restrict__ bias, float* __restrict__ C, int M, int N, int K,
    int bx, int by, unsigned short* As, unsigned short* Bs) {
  const int tid = threadIdx.x;
  const int wave = tid >> 6, lane = tid & 63;
  const int quad = lane >> 4, l16 = lane & 15;
  const int wm = wave >> 1, wn = wave & 1;
  const int bm = by * 128, bn = bx * 128;

  floatx4 acc[4][4];
#pragma unroll
  for (int i = 0; i < 4; i++)
#pragma unroll
    for (int j = 0; j < 4; j++) acc[i][j] = (floatx4){0.f, 0.f, 0.f, 0.f};

  const int srow = lane >> 2;
  const int scol = (lane & 3) * 8;

  for (int k0 = 0; k0 < K; k0 += 32) {
#pragma unroll
    for (int i = 0; i < 2; i++) {
      int c = wave * 2 + i;
      int arow = bm + c * 16 + srow;
      if (arow >= M) arow = M - 1;
      const unsigned short* ga = A + (size_t)arow * K + k0 + scol;
      __builtin_amdgcn_global_load_lds(
          (const __attribute__((address_space(1))) unsigned int*)(uintptr_t)ga,
          (__attribute__((address_space(3))) unsigned int*)(uintptr_t)(As + c * 512),
          16, 0, 0);
      int brow = bn + c * 16 + srow;
      const unsigned short* gb = Bt + (size_t)brow * K + k0 + scol;
      __builtin_amdgcn_global_load_lds(
          (const __attribute__((address_space(1))) unsigned int*)(uintptr_t)gb,
          (__attribute__((address_space(3))) unsigned int*)(uintptr_t)(Bs + c * 512),
          16, 0, 0);
    }
    __syncthreads();

    short8 af[4], bf[4];
#pragma unroll
    for (int i = 0; i < 4; i++) {
      af[i] = *(const short8*)&As[(wm * 64 + i * 16 + l16) * 32 + quad * 8];
      bf[i] = *(const short8*)&Bs[(wn * 64 + i * 16 + l16) * 32 + quad * 8];
    }
#pragma unroll
    for (int i = 0; i < 4; i++)
#pragma unroll
      for (int j = 0; j < 4; j++)
        acc[i][j] = __builtin_amdgcn_mfma_f32_16x16x32_bf16(af[i], bf[j],
                                                            acc[i][j], 0, 0, 0);
    __syncthreads();
  }

#pragma unroll
  for (int i = 0; i < 4; i++) {
    int row0 = bm + wm * 64 + i * 16 + quad * 4;
#pragma unroll
    for (int j = 0; j < 4; j++) {
      int col = bn + wn * 64 + j * 16 + l16;
      float bv = bias[col];
#pragma unroll
      for (int r = 0; r < 4; r++) {
        int row = row0 + r;
        if (row < M) C[(size_t)row * N + col] = acc[i][j][r] + bv;
      }
    }
  }
}

// ======== prep_all: cast item_feat + transpose W1,W2 + p1_hist (merged) ======
#define PREP_CAST_NB 7500     // NUM_ITEMS*FEAT_DIM/8/256
#define PREP_TW1_NB 384       // 16 x 24
#define PREP_TW2_NB 64        // 4 x 16
__global__ __launch_bounds__(256) void prep_all(
    const float* __restrict__ item_feat, unsigned short* __restrict__ Af,
    const float* __restrict__ W1, unsigned short* __restrict__ W1t,
    const float* __restrict__ W2, unsigned short* __restrict__ W2t,
    const int* __restrict__ dst, int* __restrict__ ghist, int E, int NBL) {
  __shared__ float tile[32][33];
  __shared__ int h[NBKT];
  int b = blockIdx.x, t = threadIdx.x;
  if (b < PREP_CAST_NB) {
    size_t i = (size_t)b * 256 + t;
    float4 u = ((const float4*)item_feat)[i * 2];
    float4 v = ((const float4*)item_feat)[i * 2 + 1];
    union { unsigned short s[8]; uint4 q; } p;
    p.s[0] = f2bf(u.x); p.s[1] = f2bf(u.y); p.s[2] = f2bf(u.z); p.s[3] = f2bf(u.w);
    p.s[4] = f2bf(v.x); p.s[5] = f2bf(v.y); p.s[6] = f2bf(v.z); p.s[7] = f2bf(v.w);
    ((uint4*)Af)[i] = p.q;
  } else if (b < PREP_CAST_NB + PREP_TW1_NB + PREP_TW2_NB) {
    const float* W;
    unsigned short* Wt;
    int K, N, bx, by;
    if (b < PREP_CAST_NB + PREP_TW1_NB) {
      int tb = b - PREP_CAST_NB;
      W = W1; Wt = W1t; K = FEAT_DIM; N = H1DIM;
      bx = tb % (H1DIM / 32); by = tb / (H1DIM / 32);
    } else {
      int tb = b - PREP_CAST_NB - PREP_TW1_NB;
      W = W2; Wt = W2t; K = H1DIM; N = HID;
      bx = tb % (HID / 32); by = tb / (HID / 32);
    }
    int tx = t & 31, ty = t >> 5;
#pragma unroll
    for (int kk = 0; kk < 4; kk++)
      tile[ty + kk * 8][tx] = W[(size_t)(by * 32 + ty + kk * 8) * N + bx * 32 + tx];
    __syncthreads();
#pragma unroll
    for (int kk = 0; kk < 4; kk++)
      Wt[(size_t)(bx * 32 + ty + kk * 8) * K + by * 32 + tx] =
          f2bf(tile[tx][ty + kk * 8]);
  } else {
    int hb = b - (PREP_CAST_NB + PREP_TW1_NB + PREP_TW2_NB);
    if (t < NBKT) h[t] = 0;
    __syncthreads();
    int base = hb * 8192;
    for (int i = t; i < 8192; i += 256) {
      int e = base + i;
      if (e < E) atomicAdd(&h[dst[e] >> 9], 1);
    }
    __syncthreads();
    if (t < NBKT) ghist[t * NBL + hb] = h[t];
  }
}

// ================= scan chain (unchanged) ====================================
__global__ __launch_bounds__(256) void scan_a(const int* __restrict__ in,
                                              int* __restrict__ outp,
                                              int* __restrict__ bsum, int n) {
  int i = blockIdx.x * 256 + threadIdx.x;
  int v = (i < n) ? in[i] : 0;
  int lane = threadIdx.x & 63, wid = threadIdx.x >> 6;
  int s = v;
#pragma unroll
  for (int off = 1; off < 64; off <<= 1) {
    int u = __shfl_up(s, off);
    if (lane >= off) s += u;
  }
  __shared__ int wsum[4];
  if (lane == 63) wsum[wid] = s;
  __syncthreads();
  int add = 0;
  for (int w = 0; w < wid; w++) add += wsum[w];
  int incl = s + add;
  if (i < n) outp[i] = incl - v;
  if (threadIdx.x == 255) bsum[blockIdx.x] = incl;
}

__global__ __launch_bounds__(512) void scan_b(int* __restrict__ bsum, int nb) {
  int t = threadIdx.x;
  int v = (t < nb) ? bsum[t] : 0;
  int lane = t & 63, wid = t >> 6;
  int s = v;
#pragma unroll
  for (int off = 1; off < 64; off <<= 1) {
    int u = __shfl_up(s, off);
    if (lane >= off) s += u;
  }
  __shared__ int ws[8];
  if (lane == 63) ws[wid] = s;
  __syncthreads();
  int add = 0;
  for (int w = 0; w < wid; w++) add += ws[w];
  if (t < nb) bsum[t] = s + add - v;
}

__global__ __launch_bounds__(256) void scan_c(int* __restrict__ outp,
                                              const int* __restrict__ bsum,
                                              int n) {
  int i = blockIdx.x * 256 + threadIdx.x;
  if (i < n) outp[i] += bsum[blockIdx.x];
}

// ======== gemm1 (items x W1) merged with p1_scatter ==========================
// pairs entries are PACKED u32: (dst & 511) << 17 | src   (src < 2^17)
#define G1_NB 628  // (H1DIM/128=4) x ceil(20000/128)=157
__global__ __launch_bounds__(256) void gemm1_scatter(
    const unsigned short* __restrict__ Af, const unsigned short* __restrict__ W1t,
    const float* __restrict__ b1, float* __restrict__ h1,
    const int* __restrict__ src, const int* __restrict__ dst,
    const int* __restrict__ gscan, unsigned int* __restrict__ pairs,
    int E, int NBL) {
  __shared__ __align__(16) unsigned short As[128 * 32];
  __shared__ __align__(16) unsigned short Bs[128 * 32];
  __shared__ int cur[NBKT];
  int b = blockIdx.x, t = threadIdx.x;
  if (b < G1_NB) {
    gemm_body(Af, W1t, b1, h1, NUM_ITEMS, H1DIM, FEAT_DIM, b & 3, b >> 2, As, Bs);
  } else {
    int sb = b - G1_NB;
    if (t < NBKT) cur[t] = gscan[t * NBL + sb];
    __syncthreads();
    int base = sb * 8192;
    for (int i = t; i < 8192; i += 256) {
      int e = base + i;
      if (e < E) {
        int d = dst[e];
        int pos = atomicAdd(&cur[d >> 9], 1);
        pairs[pos] = (((unsigned)d & 511u) << 17) | (unsigned)src[e];
      }
    }
  }
}

// ======== ln_relu_w512 merged with p2_build (512 threads) ====================
__global__ __launch_bounds__(512) void ln512_p2(
    const unsigned int* __restrict__ pairs, const int* __restrict__ gscan,
    int* __restrict__ rowptr, int* __restrict__ csr_src, int E, int NBL,
    const float* __restrict__ X, const float* __restrict__ g,
    const float* __restrict__ be, unsigned short* __restrict__ O) {
  __shared__ int hist[512];
  __shared__ int ws8[8];
  __shared__ float ss[4], qq[4];
  int b = blockIdx.x, t = threadIdx.x;
  if (b < NBKT) {
    // ---- p2_build body (512 threads) ----
    int base = gscan[b * NBL];
    int end = (b == NBKT - 1) ? E : gscan[(b + 1) * NBL];
    hist[t] = 0;
    __syncthreads();
    for (int i = base + t; i < end; i += 512) {
      unsigned d9 = pairs[i] >> 17;
      atomicAdd(&hist[d9], 1);
    }
    __syncthreads();
    int v = hist[t];
    int lane = t & 63, wid = t >> 6;
    int s = v;
#pragma unroll
    for (int off = 1; off < 64; off <<= 1) {
      int u = __shfl_up(s, off);
      if (lane >= off) s += u;
    }
    if (lane == 63) ws8[wid] = s;
    __syncthreads();
    int add = 0;
    for (int w = 0; w < wid; w++) add += ws8[w];
    int excl = s + add - v;
    int node = (b << 9) + t;
    if (node < NUM_NODES) rowptr[node] = base + excl;
    if (b == NBKT - 1 && t == 0) rowptr[NUM_NODES] = E;
    __syncthreads();
    hist[t] = base + excl;
    __syncthreads();
    for (int i = base + t; i < end; i += 512) {
      unsigned p = pairs[i];
      int pos = atomicAdd(&hist[p >> 17], 1);
      csr_src[pos] = (int)(p & 0x1FFFFu);
    }
  } else {
    // ---- ln_relu_w512 body (threads 0..255 active; barrier hoisted) ----
    int row = b - NBKT;
    const float* x = X + (size_t)row * H1DIM;
    float v0 = 0.f, v1 = 0.f;
    int lane = t & 63, wid = t >> 6;
    if (t < 256) {
      v0 = x[t];
      v1 = x[t + 256];
      float s = v0 + v1, q = v0 * v0 + v1 * v1;
#pragma unroll
      for (int off = 32; off > 0; off >>= 1) {
        s += __shfl_down(s, off);
        q += __shfl_down(q, off);
      }
      if (lane == 0) { ss[wid] = s; qq[wid] = q; }
    }
    __syncthreads();
    if (t < 256) {
      float S = ss[0] + ss[1] + ss[2] + ss[3];
      float Q = qq[0] + qq[1] + qq[2] + qq[3];
      float mu = S * (1.f / 512.f);
      float var = Q * (1.f / 512.f) - mu * mu;
      float rs = rsqrtf(var + LN_EPS);
      float y0 = (v0 - mu) * rs * g[t] + be[t];
      float y1 = (v1 - mu) * rs * g[t + 256] + be[t + 256];
      unsigned short* o = O + (size_t)row * H1DIM;
      o[t] = f2bf(fmaxf(y0, 0.f));
      o[t + 256] = f2bf(fmaxf(y1, 0.f));
    }
  }
}

// ======== gemm2 (h1b x W2) merged with calc_dinv =============================
#define G2_NB 157  // ceil(20000/128)
__global__ __launch_bounds__(256) void gemm2_dinv(
    const unsigned short* __restrict__ h1b, const unsigned short* __restrict__ W2t,
    const float* __restrict__ b2, float* __restrict__ h2,
    const int* __restrict__ rowptr, float* __restrict__ dinv) {
  __shared__ __align__(16) unsigned short As[128 * 32];
  __shared__ __align__(16) unsigned short Bs[128 * 32];
  int b = blockIdx.x, t = threadIdx.x;
  if (b < G2_NB) {
    gemm_body(h1b, W2t, b2, h2, NUM_ITEMS, HID, H1DIM, 0, b, As, Bs);
  } else {
    int i = (b - G2_NB) * 256 + t;
    if (i < NUM_NODES) {
      int d = rowptr[i + 1] - rowptr[i];
      dinv[i] = d > 0 ? rsqrtf((float)d) : 0.f;
    }
  }
}

// ==== gemm3_fused: LN128+ReLU (in-LDS) -> GEMM3 -> L2-normalize, 4 rows/blk ==
__global__ __launch_bounds__(128) void gemm3_fused(
    const float* __restrict__ H, const float* __restrict__ g2,
    const float* __restrict__ be2, const float* __restrict__ W3,
    const float* __restrict__ b3, float* __restrict__ meta) {
  int r0 = blockIdx.x * 4, t = threadIdx.x;
  __shared__ float hrow[4][HID];
#pragma unroll
  for (int r = 0; r < 4; r++) hrow[r][t] = H[(size_t)(r0 + r) * HID + t];
  __syncthreads();
  // LayerNorm + ReLU per row, in LDS. 2 waves; wave w handles rows 2w, 2w+1.
  int wv = t >> 6, lane = t & 63;
#pragma unroll
  for (int rr = 0; rr < 2; rr++) {
    int r = wv * 2 + rr;
    float v0 = hrow[r][lane], v1 = hrow[r][lane + 64];
    float s = v0 + v1, q = v0 * v0 + v1 * v1;
#pragma unroll
    for (int off = 32; off > 0; off >>= 1) {
      s += __shfl_down(s, off);
      q += __shfl_down(q, off);
    }
    s = __shfl(s, 0);
    q = __shfl(q, 0);
    float mu = s * (1.f / 128.f);
    float var = q * (1.f / 128.f) - mu * mu;
    float rs = rsqrtf(var + LN_EPS);
    float y0 = (v0 - mu) * rs * g2[lane] + be2[lane];
    float y1 = (v1 - mu) * rs * g2[lane + 64] + be2[lane + 64];
    hrow[r][lane] = fmaxf(y0, 0.f);
    hrow[r][lane + 64] = fmaxf(y1, 0.f);
  }
  __syncthreads();
  float s0 = 0.f, s1 = 0.f, s2 = 0.f, s3 = 0.f;
#pragma unroll 4
  for (int k = 0; k < HID; k++) {
    float w = W3[k * HID + t];
    s0 = fmaf(hrow[0][k], w, s0);
    s1 = fmaf(hrow[1][k], w, s1);
    s2 = fmaf(hrow[2][k], w, s2);
    s3 = fmaf(hrow[3][k], w, s3);
  }
  float b = b3[t];
  s0 += b; s1 += b; s2 += b; s3 += b;
  float q0 = s0 * s0, q1 = s1 * s1, q2 = s2 * s2, q3 = s3 * s3;
#pragma unroll
  for (int off = 32; off > 0; off >>= 1) {
    q0 += __shfl_down(q0, off);
    q1 += __shfl_down(q1, off);
    q2 += __shfl_down(q2, off);
    q3 += __shfl_down(q3, off);
  }
  __shared__ float qs[4][2];
  if ((t & 63) == 0) {
    int w = t >> 6;
    qs[0][w] = q0; qs[1][w] = q1; qs[2][w] = q2; qs[3][w] = q3;
  }
  __syncthreads();
  float n0 = fmaxf(sqrtf(qs[0][0] + qs[0][1]), 1e-12f);
  float n1 = fmaxf(sqrtf(qs[1][0] + qs[1][1]), 1e-12f);
  float n2 = fmaxf(sqrtf(qs[2][0] + qs[2][1]), 1e-12f);
  float n3 = fmaxf(sqrtf(qs[3][0] + qs[3][1]), 1e-12f);
  meta[(size_t)(r0 + 0) * HID + t] = s0 / n0;
  meta[(size_t)(r0 + 1) * HID + t] = s1 / n1;
  meta[(size_t)(r0 + 2) * HID + t] = s2 / n2;
  meta[(size_t)(r0 + 3) * HID + t] = s3 / n3;
}

// --------- build e0: out = alpha*e0 (fp32), xs0 = bf16(dinv*e0), 2 chunks ----
__global__ __launch_bounds__(256) void build_e0_cm2(
    const float* __restrict__ emb, const float* __restrict__ meta,
    const float* __restrict__ mw_p, const float* __restrict__ dinv,
    unsigned int* __restrict__ x0c, float* __restrict__ out) {
  size_t i = (size_t)blockIdx.x * 256 + threadIdx.x;  // 70000*64 uints, exact
  int node = (int)(i >> 6);
  int u6 = (int)(i & 63);
  int chunk = u6 >> 5, fl32 = u6 & 31;
  int f0 = chunk * 64 + fl32 * 2;
  float2 e = *(const float2*)&emb[(size_t)node * HID + f0];
  if (node >= NUM_USERS) {
    float2 m = *(const float2*)&meta[(size_t)(node - NUM_USERS) * HID + f0];
    float w = mw_p[0];
    e.x += w * m.x;
    e.y += w * m.y;
  }
  *(float2*)&out[(size_t)node * HID + f0] = make_float2(ALPHA * e.x, ALPHA * e.y);
  float d = dinv[node];
  unsigned pk = (unsigned)f2bf(d * e.x) | ((unsigned)f2bf(d * e.y) << 16);
  x0c[((size_t)chunk * NUM_NODES + node) * 32 + fl32] = pk;
}

// ------- chunked SpMM v8: 2 chunks x 64 feats (128B gathers), 8-deep ---------
#define ACC1(v)                 \
  {                             \
    a0 += bflo((v).x);          \
    a1 += bfhi((v).x);          \
    a2 += bflo((v).y);          \
    a3 += bfhi((v).y);          \
  }

__global__ __launch_bounds__(256) void spmm_chunk2(
    const int* __restrict__ rowptr, const int* __restrict__ csrc,
    const float* __restrict__ dinv, const uint2* __restrict__ xc,
    uint2* __restrict__ yc, float* __restrict__ out, int write_y) {
  int chunk = blockIdx.x & 1;
  int rowblk = blockIdx.x >> 1;
  int tid = threadIdx.x;
  int wave = tid >> 6, lane = tid & 63;
  int slot = lane >> 4, fl = lane & 15;
  int row = rowblk * 16 + wave * 4 + slot;
  bool act = row < NUM_NODES;
  int rr = act ? row : NUM_NODES - 1;
  int beg = rowptr[rr], end = rowptr[rr + 1];
  float wd = dinv[rr];
  const uint2* xq = xc + (size_t)chunk * NUM_NODES * 16 + fl;  // 16 uint2/node
  float a0 = 0.f, a1 = 0.f, a2 = 0.f, a3 = 0.f;
  int p = beg;
  // align p to a multiple of 4 so uint4 loads of the src stream are aligned
  int na = (beg + 3) & ~3;
  if (na > end) na = end;
  for (; p < na; p++) {
    int s = csrc[p];
    uint2 v = xq[(size_t)(unsigned)s * 16];
    ACC1(v)
  }
  for (; p + 8 <= end; p += 8) {
    uint4 sA = *(const uint4*)(csrc + p);
    uint4 sB = *(const uint4*)(csrc + p + 4);
    uint2 v0 = xq[(size_t)sA.x * 16];
    uint2 v1 = xq[(size_t)sA.y * 16];
    uint2 v2 = xq[(size_t)sA.z * 16];
    uint2 v3 = xq[(size_t)sA.w * 16];
    uint2 v4 = xq[(size_t)sB.x * 16];
    uint2 v5 = xq[(size_t)sB.y * 16];
    uint2 v6 = xq[(size_t)sB.z * 16];
    uint2 v7 = xq[(size_t)sB.w * 16];
    ACC1(v0) ACC1(v1) ACC1(v2) ACC1(v3)
    ACC1(v4) ACC1(v5) ACC1(v6) ACC1(v7)
  }
  if (p + 4 <= end) {
    uint4 sA = *(const uint4*)(csrc + p);
    uint2 v0 = xq[(size_t)sA.x * 16];
    uint2 v1 = xq[(size_t)sA.y * 16];
    uint2 v2 = xq[(size_t)sA.z * 16];
    uint2 v3 = xq[(size_t)sA.w * 16];
    ACC1(v0) ACC1(v1) ACC1(v2) ACC1(v3)
    p += 4;
  }
  for (; p < end; p++) {
    int s = csrc[p];
    uint2 v = xq[(size_t)(unsigned)s * 16];
    ACC1(v)
  }
  // y = dinv[row] * s
  float y0 = wd * a0, y1 = wd * a1, y2 = wd * a2, y3 = wd * a3;
  if (act) {
    if (write_y) {
      unsigned p0 = (unsigned)f2bf(wd * y0) | ((unsigned)f2bf(wd * y1) << 16);
      unsigned p1 = (unsigned)f2bf(wd * y2) | ((unsigned)f2bf(wd * y3) << 16);
      yc[((size_t)chunk * NUM_NODES + row) * 16 + fl] = make_uint2(p0, p1);
    }
    float4* op = (float4*)&out[(size_t)row * HID + chunk * 64 + fl * 4];
    float4 po = *op;
    po.x += ALPHA * y0;
    po.y += ALPHA * y1;
    po.z += ALPHA * y2;
    po.w += ALPHA * y3;
    *op = po;
  }
}

// ---------------- launcher ---------------------------------------------------
extern "C" void kernel_launch(void* const* d_in, const int* in_sizes, int n_in,
                              void* d_out, int out_size, void* d_ws,
                              size_t ws_size, hipStream_t stream) {
  const int* edge = (const int*)d_in[0];
  const float* item_feat = (const float*)d_in[1];
  const float* emb = (const float*)d_in[2];
  const float* W1 = (const float*)d_in[3];
  const float* b1 = (const float*)d_in[4];
  const float* g1 = (const float*)d_in[5];
  const float* be1 = (const float*)d_in[6];
  const float* W2 = (const float*)d_in[7];
  const float* b2 = (const float*)d_in[8];
  const float* g2 = (const float*)d_in[9];
  const float* be2 = (const float*)d_in[10];
  const float* W3 = (const float*)d_in[11];
  const float* b3 = (const float*)d_in[12];
  const float* mw = (const float*)d_in[13];
  float* out = (float*)d_out;

  const int E = in_sizes[0] / 2;
  const int* src = edge;
  const int* dst = edge + E;
  const int NBL = (E + 8191) / 8192;        // 245 P1 blocks
  const int nScan = NBKT * NBL;             // 33565
  const int NBs = (nScan + 255) / 256;      // 132

  // ---- workspace layout (lifetime-checked for the CONCURRENT merged chains):
  //  h1    @0       [0,40.96M)      gemm1 -> ln512_p2 (then dead)
  //  meta  @0       [0,10.24M)      gemm3_fused -> build_e0 (h1 dead)
  //  xB    @0       [0,17.92M)      spmm1 -> spmm2 (meta dead)
  //  xC    @18M     [18,35.92M)     spmm2 -> spmm3
  //  h2    @40.96M  [40.96,51.2M)   gemm2 -> gemm3_fused
  //  h1b   @51.2M   [51.2,71.68M)   ln512_p2 -> gemm2
  //  xA    @51.2M   (h1b dead)      build_e0 -> spmm1
  //  pairs @72M     [72,80M) u32    gemm1_scatter -> ln512_p2
  //  rowptr@80.5M, dinv@81M, ghist@81.5M, gscan@81.8M, bsum@82.1M
  //  csr_src@82.5M  [82.5,90.5M)    ln512_p2 -> spmm (over dead Af head)
  //  Af    @87.04M  [87.04,117.76M) prep -> gemm1 (then dead)
  //  W1t   @122.88M, W2t @123.67M
  char* ws = (char*)d_ws;
  float* h1 = (float*)(ws + 0);
  float* meta = (float*)(ws + 0);
  uint2* xB = (uint2*)(ws + 0);
  uint2* xC = (uint2*)(ws + 18000000);
  float* h2 = (float*)(ws + 40960000);
  unsigned short* h1b = (unsigned short*)(ws + 51200000);
  uint2* xA = (uint2*)(ws + 51200000);
  unsigned int* pairs = (unsigned int*)(ws + 72000000);
  int* rowptr = (int*)(ws + 80500000);
  float* dinv = (float*)(ws + 81000000);
  int* ghist = (int*)(ws + 81500000);
  int* gscan = (int*)(ws + 81800000);
  int* bsum = (int*)(ws + 82100000);
  int* csr_src = (int*)(ws + 82500000);
  unsigned short* Af = (unsigned short*)(ws + 87040000);
  unsigned short* W1t = (unsigned short*)(ws + 122880000);
  unsigned short* W2t = (unsigned short*)(ws + 123666432);

  // 1) prep: cast + transposes + p1_hist (independent work, one launch)
  prep_all<<<PREP_CAST_NB + PREP_TW1_NB + PREP_TW2_NB + NBL, 256, 0, stream>>>(
      item_feat, Af, W1, W1t, W2, W2t, dst, ghist, E, NBL);

  // 2-4) scan chain
  scan_a<<<NBs, 256, 0, stream>>>(ghist, gscan, bsum, nScan);
  scan_b<<<1, 512, 0, stream>>>(bsum, NBs);
  scan_c<<<NBs, 256, 0, stream>>>(gscan, bsum, nScan);

  // 5) gemm1 (MFMA) || p1_scatter
  gemm1_scatter<<<G1_NB + NBL, 256, 0, stream>>>(Af, W1t, b1, h1, src, dst,
                                                 gscan, pairs, E, NBL);

  // 6) ln_relu_w512 || p2_build
  ln512_p2<<<NBKT + NUM_ITEMS, 512, 0, stream>>>(pairs, gscan, rowptr, csr_src,
                                                 E, NBL, h1, g1, be1, h1b);

  // 7) gemm2 (MFMA) || calc_dinv
  gemm2_dinv<<<G2_NB + (NUM_NODES + 255) / 256, 256, 0, stream>>>(
      h1b, W2t, b2, h2, rowptr, dinv);

  // 8) LN128+ReLU + GEMM3 + L2-normalize fused
  gemm3_fused<<<NUM_ITEMS / 4, 128, 0, stream>>>(h2, g2, be2, W3, b3, meta);

  // 9) e0 -> out (fp32) + xs0 = bf16(dinv*e0), 2 chunks x 64 feats
  build_e0_cm2<<<(NUM_NODES * 64) / 256, 256, 0, stream>>>(
      emb, meta, mw, dinv, (unsigned int*)xA, out);

  // 10-12) 3 propagation layers (2-chunked, 128B gathers)
  const int RG = ((NUM_NODES + 15) / 16) * 2;  // 4375*2 = 8750 blocks
  spmm_chunk2<<<RG, 256, 0, stream>>>(rowptr, csr_src, dinv, xA, xB, out, 1);
  spmm_chunk2<<<RG, 256, 0, stream>>>(rowptr, csr_src, dinv, xB, xC, out, 1);
  spmm_chunk2<<<RG, 256, 0, stream>>>(rowptr, csr_src, dinv, xC, nullptr, out, 0);
}